// Round 14
// baseline (96.075 us; speedup 1.0000x reference)
//
#include <hip/hip_runtime.h>
#include <hip/hip_bf16.h>
#include <math.h>

// Problem constants
#define NB   16      // batch
#define NIN  512
#define NN   2048
#define KN   28672   // K*N
#define INVNONE 0x7fffffff
#define NC   32      // n-chunks for k3 (nper = 64)
#define UN   8       // loads batched per iteration in k3

// ---------------------------------------------------------------------------
// k1: partial GEMM i_in = inputs @ W, f64 accumulation, deterministic order.
// part[ks][b][n], ks in [0,16) covering k = ks*32 .. ks*32+31.
// grid (32 n-chunks, 16 ks), block = 64 threads (one wave, 64 n's).
// Also clears zmask (ks==0 blocks) and inits inv[] (all blocks, 1 elem/thread).
__global__ __launch_bounds__(64) void k1_gemm(const float* __restrict__ inputs,
                                              const float* __restrict__ W,
                                              double* __restrict__ part,
                                              unsigned int* __restrict__ zmask,
                                              int* __restrict__ inv) {
    const int n  = blockIdx.x * 64 + threadIdx.x;
    const int ks = blockIdx.y;
    if (ks == 0) zmask[n] = 0u;                 // fused clear
    int fid = (ks * 32 + blockIdx.x) * 64 + threadIdx.x;   // [0, 32768)
    if (fid < KN) inv[fid] = INVNONE;           // fused inv init
    const int k0 = ks * 32;
    double acc[16];
    #pragma unroll
    for (int b = 0; b < 16; ++b) acc[b] = 0.0;
    #pragma unroll 8
    for (int kk = 0; kk < 32; ++kk) {           // 8 W-loads batched in flight
        double w = (double)W[(size_t)(k0 + kk) * NN + n];   // coalesced 256B/wave
        #pragma unroll
        for (int b = 0; b < 16; ++b)                        // uniform scalar loads
            acc[b] += w * (double)inputs[b * NIN + k0 + kk];
    }
    #pragma unroll
    for (int b = 0; b < 16; ++b)
        part[(size_t)(ks * 16 + b) * NN + n] = acc[b];
}

// ---------------------------------------------------------------------------
// kM: inv[col] = min slot with ridx[slot]==col (atomicMin -> deterministic).
__global__ __launch_bounds__(256) void kM_min(const int* __restrict__ ridx,
                                              int* __restrict__ inv) {
    int i = blockIdx.x * 256 + threadIdx.x;     // [0, 2048)
    atomicMin(&inv[ridx[i]], i);
}

// ---------------------------------------------------------------------------
// k2: deterministic reduce of 16 partials + LIF update. Writes new_z, new_v,
// and per-neuron 16-bit spike mask (atomicOr = order-independent).
__global__ __launch_bounds__(256) void k2_point(const double* __restrict__ part,
                                                const float* __restrict__ old_v,
                                                const float* __restrict__ old_spike,
                                                const int* __restrict__ tt_p,
                                                float* __restrict__ out,      // z @0, v @32768
                                                unsigned int* __restrict__ zmask) {
    int gid = blockIdx.x * 256 + threadIdx.x;   // [0, 32768)
    int b = gid >> 11, n = gid & (NN - 1);
    double s = 0.0;
    #pragma unroll
    for (int ks = 0; ks < 16; ++ks)             // fixed order -> deterministic
        s += part[(size_t)(ks * 16 + b) * NN + n];
    double tt   = (double)tt_p[0];
    double bias = 0.5 * sin(2.0 * 3.14159265358979323846 * 4.0 * (0.001 * tt));
    double d    = 0.9512294245007140;           // exp(-1/20)
    double i_in = s + bias;
    double nv   = d * (double)old_v[gid] + (1.0 - d) * i_in
                  - 0.03 * (double)old_spike[gid];
    bool z = nv > 0.03;                          // v_scaled > 0  <=>  nv > THR
    out[gid]           = z ? 1.0f : 0.0f;
    out[32768 + gid]   = (float)nv;
    if (z) atomicOr(&zmask[n], 1u << b);
}

// ---------------------------------------------------------------------------
// k3: streamed masked row-sum of B (= new_z @ B). r9 structure, ONE change:
// float per thread (16 acc VGPRs, not 32) + __launch_bounds__(128, 8) so the
// allocator stays <=64 VGPR -> 8 waves/SIMD resident (r2-r9 compiled to 68
// VGPR -> only 4/SIMD: the hidden occupancy cap). UN=8 unchanged; per-column
// fmaf order identical to r9 -> bit-identical output.
// Grid 224 x 32 = 7168 blocks of 128 thr = 28 blocks/CU, exactly balanced.
__global__ __launch_bounds__(128, 8) void k3_stream(const float* __restrict__ B,
                                                    const unsigned int* __restrict__ zmask,
                                                    const int* __restrict__ inv,
                                                    float* __restrict__ compact,
                                                    int nper) {
    __shared__ unsigned int smask[64];
    const int t   = threadIdx.x;
    const int col = blockIdx.x * 128 + t;        // [0, 28672)
    const int n0  = blockIdx.y * nper;           // nper = 64
    if (t < 64) smask[t] = zmask[n0 + t];
    __syncthreads();

    float acc[16];
    #pragma unroll
    for (int b = 0; b < 16; ++b) acc[b] = 0.f;

    const float* p = B + (size_t)n0 * KN + col;
    for (int j = 0; j < nper; j += UN) {
        float v[UN];
        #pragma unroll
        for (int u = 0; u < UN; ++u)             // batched 4B loads (256B/wave)
            v[u] = p[(size_t)(j + u) * KN];
        #pragma unroll
        for (int u = 0; u < UN; ++u) {
            unsigned int m = (unsigned int)
                __builtin_amdgcn_readfirstlane((int)smask[j + u]);
            #pragma unroll
            for (int b = 0; b < 16; ++b) {
                float s = (m & (1u << b)) ? 1.0f : 0.0f;   // SGPR cselect
                acc[b] = fmaf(s, v[u], acc[b]);            // exact: +v or +0
            }
        }
    }
    // Compact store: only columns that are some slot's representative.
    int r = inv[col];
    if (r != INVNONE) {
        float* cbase = compact + (size_t)blockIdx.y * 16 * 2048;
        #pragma unroll
        for (int b = 0; b < 16; ++b) cbase[b * 2048 + r] = acc[b];
    }
}

// ---------------------------------------------------------------------------
// k4: per output slot, sum NC chunk-partials of its representative column
// (fixed order). compact is 4 MB -> L2-hot.
__global__ __launch_bounds__(128) void k4_gather(const float* __restrict__ compact,
                                                 const int* __restrict__ ridx,
                                                 const int* __restrict__ inv,
                                                 float* __restrict__ out_z2) {
    int gid = blockIdx.x * 128 + threadIdx.x;   // [0, 32768)
    int b = gid >> 11, i = gid & (NN - 1);
    int rep = inv[ridx[i]];                     // always valid (ridx[i] needed)
    float acc = 0.f;
    #pragma unroll 8
    for (int c = 0; c < NC; ++c)                // independent loads, pipelined
        acc += compact[(size_t)(c * 16 + b) * 2048 + rep];
    out_z2[gid] = acc;
}

// ---------------------------------------------------------------------------
extern "C" void kernel_launch(void* const* d_in, const int* in_sizes, int n_in,
                              void* d_out, int out_size, void* d_ws, size_t ws_size,
                              hipStream_t stream) {
    const float* inputs    = (const float*)d_in[0];
    const float* old_v     = (const float*)d_in[1];
    const float* old_spike = (const float*)d_in[2];
    const float* W         = (const float*)d_in[3];
    const float* Bw        = (const float*)d_in[4];
    const int*   ridx      = (const int*)d_in[5];
    const int*   tt        = (const int*)d_in[6];
    float* out = (float*)d_out;

    // ws layout: [0,4MB) f64 partials | 64KB zmask | 128KB inv | 4MB compact
    char* ws = (char*)d_ws;
    double*       part    = (double*)ws;
    unsigned int* zmask   = (unsigned int*)(ws + (4u << 20));
    int*          inv     = (int*)(ws + (4u << 20) + (64u << 10));
    float*        compact = (float*)(ws + (4u << 20) + (192u << 10));

    const int nper = NN / NC;                    // 64

    k1_gemm <<<dim3(32, 16), 64, 0, stream>>>(inputs, W, part, zmask, inv);
    kM_min  <<<8, 256, 0, stream>>>(ridx, inv);
    k2_point<<<128, 256, 0, stream>>>(part, old_v, old_spike, tt, out, zmask);
    k3_stream<<<dim3(224, NC), 128, 0, stream>>>(Bw, zmask, inv, compact, nper);
    k4_gather<<<256, 128, 0, stream>>>(compact, ridx, inv, out + 65536);
}

// Round 15
// 61.423 us; speedup vs baseline: 1.5641x; 1.5641x over previous
//
#include <hip/hip_runtime.h>
#include <hip/hip_bf16.h>
#include <math.h>

// Problem constants
#define NB   16      // batch
#define NIN  512
#define NN   2048
#define KN   28672   // K*N
#define KN4  7168    // KN/4
#define INVNONE 0x7fffffff
#define NC   32      // n-chunks for k3 (nper = 64)
#define UN   4       // float4 loads batched per iteration in k3

// ---------------------------------------------------------------------------
// k1: partial GEMM i_in = inputs @ W, f64 accumulation, deterministic order.
// part[ks][b][n], ks in [0,16) covering k = ks*32 .. ks*32+31.
// grid (32 n-chunks, 16 ks), block = 64 threads (one wave, 64 n's).
// Also clears zmask (ks==0 blocks) and inits inv[] (all blocks, 1 elem/thread).
__global__ __launch_bounds__(64) void k1_gemm(const float* __restrict__ inputs,
                                              const float* __restrict__ W,
                                              double* __restrict__ part,
                                              unsigned int* __restrict__ zmask,
                                              int* __restrict__ inv) {
    const int n  = blockIdx.x * 64 + threadIdx.x;
    const int ks = blockIdx.y;
    if (ks == 0) zmask[n] = 0u;                 // fused clear
    int fid = (ks * 32 + blockIdx.x) * 64 + threadIdx.x;   // [0, 32768)
    if (fid < KN) inv[fid] = INVNONE;           // fused inv init
    const int k0 = ks * 32;
    double acc[16];
    #pragma unroll
    for (int b = 0; b < 16; ++b) acc[b] = 0.0;
    #pragma unroll 8
    for (int kk = 0; kk < 32; ++kk) {           // 8 W-loads batched in flight
        double w = (double)W[(size_t)(k0 + kk) * NN + n];   // coalesced 256B/wave
        #pragma unroll
        for (int b = 0; b < 16; ++b)                        // uniform scalar loads
            acc[b] += w * (double)inputs[b * NIN + k0 + kk];
    }
    #pragma unroll
    for (int b = 0; b < 16; ++b)
        part[(size_t)(ks * 16 + b) * NN + n] = acc[b];
}

// ---------------------------------------------------------------------------
// k2: deterministic reduce of 16 partials + LIF update. Writes new_z, new_v,
// per-neuron 16-bit spike mask (atomicOr = order-independent), and fused
// kM: inv[col] = min slot with ridx[slot]==col (atomicMin -> deterministic;
// inv initialized by k1, which completes before k2 in stream order).
__global__ __launch_bounds__(256) void k2_point(const double* __restrict__ part,
                                                const float* __restrict__ old_v,
                                                const float* __restrict__ old_spike,
                                                const int* __restrict__ tt_p,
                                                const int* __restrict__ ridx,
                                                float* __restrict__ out,      // z @0, v @32768
                                                unsigned int* __restrict__ zmask,
                                                int* __restrict__ inv) {
    int gid = blockIdx.x * 256 + threadIdx.x;   // [0, 32768)
    if (gid < NN) atomicMin(&inv[ridx[gid]], gid);   // fused kM
    int b = gid >> 11, n = gid & (NN - 1);
    double s = 0.0;
    #pragma unroll
    for (int ks = 0; ks < 16; ++ks)             // fixed order -> deterministic
        s += part[(size_t)(ks * 16 + b) * NN + n];
    double tt   = (double)tt_p[0];
    double bias = 0.5 * sin(2.0 * 3.14159265358979323846 * 4.0 * (0.001 * tt));
    double d    = 0.9512294245007140;           // exp(-1/20)
    double i_in = s + bias;
    double nv   = d * (double)old_v[gid] + (1.0 - d) * i_in
                  - 0.03 * (double)old_spike[gid];
    bool z = nv > 0.03;                          // v_scaled > 0  <=>  nv > THR
    out[gid]           = z ? 1.0f : 0.0f;
    out[32768 + gid]   = (float)nv;
    if (z) atomicOr(&zmask[n], 1u << b);
}

// ---------------------------------------------------------------------------
// k3: streamed masked row-sum of B (= new_z @ B). r9 loop shape, but FLOAT4
// loads: 1 KB per wave-instruction (the width term that r14 proved dominant).
// acc = float4[16] (64 VGPR, static .xyzw indices); UN=4 in-flight buffer.
// Expected ~95-110 VGPR -> 4 waves/SIMD = 16 waves/CU >= grid's 14/CU.
// Even serialized 1-load-in-flight: 14 waves x 1KB / 900cyc -> ~9.5 TB/s
// ceiling, so k3 becomes memory-bound, not issue-bound.
// Grid 56 x 32 = 1792 blocks of 128 thr = 7 blocks/CU, exactly balanced.
__global__ __launch_bounds__(128) void k3_stream(const float4* __restrict__ B4,
                                                 const unsigned int* __restrict__ zmask,
                                                 const int* __restrict__ inv,
                                                 float* __restrict__ compact,
                                                 int nper) {
    __shared__ unsigned int smask[64];
    const int t    = threadIdx.x;
    const int col4 = blockIdx.x * 128 + t;       // [0, 7168)
    const int n0   = blockIdx.y * nper;          // nper = 64
    if (t < 64) smask[t] = zmask[n0 + t];
    __syncthreads();

    float4 acc[16];
    #pragma unroll
    for (int b = 0; b < 16; ++b) acc[b] = make_float4(0.f, 0.f, 0.f, 0.f);

    const float4* p = B4 + (size_t)n0 * KN4 + col4;
    for (int j = 0; j < nper; j += UN) {
        float4 v[UN];
        #pragma unroll
        for (int u = 0; u < UN; ++u)             // batched 16B loads (1KB/wave)
            v[u] = p[(size_t)(j + u) * KN4];
        #pragma unroll
        for (int u = 0; u < UN; ++u) {
            unsigned int m = (unsigned int)
                __builtin_amdgcn_readfirstlane((int)smask[j + u]);
            #pragma unroll
            for (int b = 0; b < 16; ++b) {
                float s = (m & (1u << b)) ? 1.0f : 0.0f;   // SGPR cselect
                acc[b].x = fmaf(s, v[u].x, acc[b].x);      // exact: +v or +0
                acc[b].y = fmaf(s, v[u].y, acc[b].y);
                acc[b].z = fmaf(s, v[u].z, acc[b].z);
                acc[b].w = fmaf(s, v[u].w, acc[b].w);
            }
        }
    }
    // Compact store: only columns that are some slot's representative.
    float* cbase = compact + (size_t)blockIdx.y * 16 * 2048;
    int r0 = inv[4 * col4 + 0];
    int r1 = inv[4 * col4 + 1];
    int r2 = inv[4 * col4 + 2];
    int r3 = inv[4 * col4 + 3];
    if (r0 != INVNONE) {
        #pragma unroll
        for (int b = 0; b < 16; ++b) cbase[b * 2048 + r0] = acc[b].x;
    }
    if (r1 != INVNONE) {
        #pragma unroll
        for (int b = 0; b < 16; ++b) cbase[b * 2048 + r1] = acc[b].y;
    }
    if (r2 != INVNONE) {
        #pragma unroll
        for (int b = 0; b < 16; ++b) cbase[b * 2048 + r2] = acc[b].z;
    }
    if (r3 != INVNONE) {
        #pragma unroll
        for (int b = 0; b < 16; ++b) cbase[b * 2048 + r3] = acc[b].w;
    }
}

// ---------------------------------------------------------------------------
// k4: per output slot, sum NC chunk-partials of its representative column
// (fixed order). compact is 4 MB -> L2-hot.
__global__ __launch_bounds__(128) void k4_gather(const float* __restrict__ compact,
                                                 const int* __restrict__ ridx,
                                                 const int* __restrict__ inv,
                                                 float* __restrict__ out_z2) {
    int gid = blockIdx.x * 128 + threadIdx.x;   // [0, 32768)
    int b = gid >> 11, i = gid & (NN - 1);
    int rep = inv[ridx[i]];                     // always valid (ridx[i] needed)
    float acc = 0.f;
    #pragma unroll 8
    for (int c = 0; c < NC; ++c)                // independent loads, pipelined
        acc += compact[(size_t)(c * 16 + b) * 2048 + rep];
    out_z2[gid] = acc;
}

// ---------------------------------------------------------------------------
extern "C" void kernel_launch(void* const* d_in, const int* in_sizes, int n_in,
                              void* d_out, int out_size, void* d_ws, size_t ws_size,
                              hipStream_t stream) {
    const float* inputs    = (const float*)d_in[0];
    const float* old_v     = (const float*)d_in[1];
    const float* old_spike = (const float*)d_in[2];
    const float* W         = (const float*)d_in[3];
    const float* Bw        = (const float*)d_in[4];
    const int*   ridx      = (const int*)d_in[5];
    const int*   tt        = (const int*)d_in[6];
    float* out = (float*)d_out;

    // ws layout: [0,4MB) f64 partials | 64KB zmask | 128KB inv | 4MB compact
    char* ws = (char*)d_ws;
    double*       part    = (double*)ws;
    unsigned int* zmask   = (unsigned int*)(ws + (4u << 20));
    int*          inv     = (int*)(ws + (4u << 20) + (64u << 10));
    float*        compact = (float*)(ws + (4u << 20) + (192u << 10));

    const int nper = NN / NC;                    // 64

    k1_gemm <<<dim3(32, 16), 64, 0, stream>>>(inputs, W, part, zmask, inv);
    k2_point<<<128, 256, 0, stream>>>(part, old_v, old_spike, tt, ridx,
                                      out, zmask, inv);
    k3_stream<<<dim3(56, NC), 128, 0, stream>>>((const float4*)Bw, zmask,
                                                inv, compact, nper);
    k4_gather<<<256, 128, 0, stream>>>(compact, ridx, inv, out + 65536);
}